// Round 1
// baseline (425.288 us; speedup 1.0000x reference)
//
#include <hip/hip_runtime.h>
#include <stdint.h>

// Problem constants (derived from in_sizes at launch; these are for sizing logic)
//   N_NODES = 100000, N_EDGES = 3200000, D = 64, NHID = 128
//
// Decomposition:
//   h = relu([z_row | z_col] @ W1^T + b1)
//     = relu( z_row @ W1[:, :64]^T + z_col @ W1[:, 64:]^T + b1 )
//   out = h @ W2^T + b2
// Precompute per node:  U[n][j] = sum_k z[n][k] * W1[j][k]      + b1[j]   (j in 0..127)
//                       V[n][j] = sum_k z[n][k] * W1[j][64+k]             (j in 0..127)
// Stored as bf16 in workspace (tolerance is bf16-floor, err ~2e-3 << 6.2e-2).
// Per edge:  out[e] = b2 + sum_j W2[j] * relu(U[row[e]][j] + V[col[e]][j])

__device__ inline unsigned short f2bf(float f) {
    uint32_t u = __builtin_bit_cast(uint32_t, f);
    uint32_t r = (u + 0x7FFFu + ((u >> 16) & 1u)) >> 16;  // RNE
    return (unsigned short)r;
}

// ---------------- Kernel 1: node precompute  U,V = z @ Wcat -------------------
// Block: 256 threads = 4 waves. Each wave processes one node per iteration.
// LDS: WT[k][j] = Wcat^T, 64x256 fp32 = 64 KB (conflict-free b128 reads).
__global__ __launch_bounds__(256) void node_precompute(
    const float* __restrict__ z, const float* __restrict__ W1,
    const float* __restrict__ b1,
    unsigned short* __restrict__ U, unsigned short* __restrict__ V,
    int n_nodes)
{
    __shared__ __align__(16) float WT[64][256];
    __shared__ float zr[4][64];

    const int tid = threadIdx.x;

    // Load WT: WT[k][j] = (j<128) ? W1[j][k] : W1[j-128][64+k]
    // lane j = tid (consecutive banks on write -> conflict-free writes)
#pragma unroll 8
    for (int k = 0; k < 64; ++k) {
        float wv = (tid < 128) ? W1[tid * 128 + k]
                               : W1[(tid - 128) * 128 + 64 + k];
        WT[k][tid] = wv;
    }
    __syncthreads();

    const int w = tid >> 6;   // wave id 0..3
    const int l = tid & 63;   // lane id
    const int jbase = 4 * l;  // this lane's 4 output columns (j in 0..255)

    // Bias only applies to the U half (j < 128 <=> l < 32)
    float4 bias = make_float4(0.f, 0.f, 0.f, 0.f);
    if (l < 32) bias = *(const float4*)&b1[jbase];

    const int step = gridDim.x * 4;
    const int iters = (n_nodes + step - 1) / step;  // uniform trip count for barriers
    int n = blockIdx.x * 4 + w;

    for (int it = 0; it < iters; ++it, n += step) {
        const bool valid = (n < n_nodes);
        if (valid) zr[w][l] = z[(size_t)n * 64 + l];
        __syncthreads();
        if (valid) {
            float a0 = 0.f, a1 = 0.f, a2 = 0.f, a3 = 0.f;
#pragma unroll 8
            for (int k = 0; k < 64; ++k) {
                float zv = zr[w][k];                     // LDS broadcast (free)
                float4 wv = *(const float4*)&WT[k][jbase]; // ds_read_b128, conflict-free
                a0 = fmaf(zv, wv.x, a0);
                a1 = fmaf(zv, wv.y, a1);
                a2 = fmaf(zv, wv.z, a2);
                a3 = fmaf(zv, wv.w, a3);
            }
            a0 += bias.x; a1 += bias.y; a2 += bias.z; a3 += bias.w;
            uint2 packed;
            packed.x = (uint32_t)f2bf(a0) | ((uint32_t)f2bf(a1) << 16);
            packed.y = (uint32_t)f2bf(a2) | ((uint32_t)f2bf(a3) << 16);
            if (l < 32) {
                *(uint2*)&U[(size_t)n * 128 + jbase] = packed;
            } else {
                *(uint2*)&V[(size_t)n * 128 + (jbase - 128)] = packed;
            }
        }
        __syncthreads();  // WAR protection on zr
    }
}

// ---------------- Kernel 2: per-edge gather + relu + dot ----------------------
// 16 lanes per edge; each lane loads 16 B of U[row] and 16 B of V[col]
// (a 16-lane group covers the full 256 B row, coalesced), then shfl-reduce.
__device__ inline float acc2(uint32_t u, uint32_t v, float w0, float w1, float s) {
    float ul = __builtin_bit_cast(float, u << 16);
    float uh = __builtin_bit_cast(float, u & 0xFFFF0000u);
    float vl = __builtin_bit_cast(float, v << 16);
    float vh = __builtin_bit_cast(float, v & 0xFFFF0000u);
    s = fmaf(fmaxf(ul + vl, 0.f), w0, s);
    s = fmaf(fmaxf(uh + vh, 0.f), w1, s);
    return s;
}

__global__ __launch_bounds__(256) void edge_kernel(
    const unsigned short* __restrict__ U, const unsigned short* __restrict__ V,
    const int* __restrict__ row, const int* __restrict__ col,
    const float* __restrict__ W2, const float* __restrict__ b2,
    float* __restrict__ out, int E)
{
    const int sub = threadIdx.x & 15;           // lane within edge-group
    const float4 w2a = *(const float4*)&W2[sub * 8];
    const float4 w2b = *(const float4*)&W2[sub * 8 + 4];
    const float bb = b2[0];

    int g = blockIdx.x * 16 + (threadIdx.x >> 4);
    const int stride = gridDim.x * 16;

    for (; g < E; g += stride) {
        const int r = row[g];
        const int c = col[g];
        uint4 uu = *(const uint4*)(U + (size_t)r * 128 + sub * 8);
        uint4 vv = *(const uint4*)(V + (size_t)c * 128 + sub * 8);
        float s = 0.f;
        s = acc2(uu.x, vv.x, w2a.x, w2a.y, s);
        s = acc2(uu.y, vv.y, w2a.z, w2a.w, s);
        s = acc2(uu.z, vv.z, w2b.x, w2b.y, s);
        s = acc2(uu.w, vv.w, w2b.z, w2b.w, s);
        // reduce across the 16 lanes of this edge-group
        s += __shfl_xor(s, 1, 16);
        s += __shfl_xor(s, 2, 16);
        s += __shfl_xor(s, 4, 16);
        s += __shfl_xor(s, 8, 16);
        if (sub == 0) out[g] = s + bb;
    }
}

extern "C" void kernel_launch(void* const* d_in, const int* in_sizes, int n_in,
                              void* d_out, int out_size, void* d_ws, size_t ws_size,
                              hipStream_t stream) {
    const float* z  = (const float*)d_in[0];
    const int*   row = (const int*)d_in[1];
    const int*   col = (const int*)d_in[2];
    const float* W1 = (const float*)d_in[3];
    const float* b1 = (const float*)d_in[4];
    const float* W2 = (const float*)d_in[5];
    const float* b2 = (const float*)d_in[6];
    float* out = (float*)d_out;

    const int n_nodes = in_sizes[0] / 64;   // z is [N, 64]
    const int E = in_sizes[1];

    unsigned short* U = (unsigned short*)d_ws;
    unsigned short* V = U + (size_t)n_nodes * 128;
    // workspace use: n_nodes*128*2 bf16 = 51.2 MB

    node_precompute<<<512, 256, 0, stream>>>(z, W1, b1, U, V, n_nodes);

    edge_kernel<<<4096, 256, 0, stream>>>(U, V, row, col, W2, b2, out, E);
}

// Round 2
// 326.787 us; speedup vs baseline: 1.3014x; 1.3014x over previous
//
#include <hip/hip_runtime.h>
#include <stdint.h>

// Decomposition (unchanged from R1):
//   UV[n][j] = z[n] . Wcat[:,j] (+ b1[j] for j<128), stored bf16, j in 0..255
//     where Wcat[k][j] = (j<128) ? W1[j][k] : W1[j-128][64+k]
//   out[e] = b2 + sum_j W2[j] * relu(UV[row[e]][j] + UV[col[e]][128+j])
//
// R2 change: node precompute now uses MFMA 16x16x32 bf16 with weights held in
// registers (B-fragments loaded once per wave), instead of the LDS-rebroadcast
// VALU GEMM that re-read 64 KB of LDS per node (~205 us -> target ~25 us).

typedef __attribute__((ext_vector_type(8))) short bf16x8;
typedef __attribute__((ext_vector_type(4))) float f32x4;

__device__ inline unsigned short f2bf(float f) {
    uint32_t u = __builtin_bit_cast(uint32_t, f);
    uint32_t r = (u + 0x7FFFu + ((u >> 16) & 1u)) >> 16;  // RNE
    return (unsigned short)r;
}

// ---------------- Kernel 1: node precompute via MFMA --------------------------
// Block = 256 threads = 4 waves. Wave w owns output cols [w*64, w*64+64) as
// 4 N-tiles of 16. B-fragments (weights, bf16) are loaded ONCE into registers:
//   B[k][n] with n = w*64 + nt*16 + (lane&15), k = kh*32 + (lane>>4)*8 + j.
// Per iteration: one 16-node tile of z staged to LDS as bf16 (padded rows to
// kill b128 bank conflicts), A-frags read via ds_read_b128, 8 MFMAs/wave.
__global__ __launch_bounds__(256) void node_precompute_mfma(
    const float* __restrict__ z, const float* __restrict__ W1,
    const float* __restrict__ b1, unsigned short* __restrict__ UV,
    int n_nodes)
{
    __shared__ __align__(16) unsigned short zs[16][72];  // 72 = 64 + 8 pad (144 B row, 16B-aligned)

    const int tid = threadIdx.x;
    const int w  = tid >> 6;    // wave 0..3
    const int l  = tid & 63;
    const int lm = l & 15;      // A-row / B-col / C-col sublane
    const int q  = l >> 4;      // quad 0..3

    // ---- one-time: weight B-fragments + per-col bias into registers ----
    bf16x8 bfrag[4][2];
    float  bias[4];
#pragma unroll
    for (int nt = 0; nt < 4; ++nt) {
        const int n = w * 64 + nt * 16 + lm;               // output col 0..255
        const float* wrow = (n < 128) ? (W1 + (size_t)n * 128)
                                      : (W1 + (size_t)(n - 128) * 128 + 64);
#pragma unroll
        for (int kh = 0; kh < 2; ++kh) {
            const int k0 = kh * 32 + q * 8;
            bf16x8 bb;
#pragma unroll
            for (int j = 0; j < 8; ++j) bb[j] = (short)f2bf(wrow[k0 + j]);
            bfrag[nt][kh] = bb;
        }
        bias[nt] = (n < 128) ? b1[n] : 0.f;
    }

    const int ntiles = (n_nodes + 15) >> 4;
    const int iters = (ntiles + gridDim.x - 1) / gridDim.x;  // uniform for barriers
    int tile = blockIdx.x;

    const int srow = tid >> 4;        // staging: thread -> (row, 4-float chunk)
    const int scol = (tid & 15) * 4;

    for (int it = 0; it < iters; ++it, tile += gridDim.x) {
        const int node0 = tile * 16;
        if (tile < ntiles) {
            float4 zv = make_float4(0.f, 0.f, 0.f, 0.f);
            if (node0 + srow < n_nodes)
                zv = *(const float4*)(z + (size_t)(node0 + srow) * 64 + scol);
            unsigned short* p = &zs[srow][scol];
            p[0] = f2bf(zv.x); p[1] = f2bf(zv.y); p[2] = f2bf(zv.z); p[3] = f2bf(zv.w);
        }
        __syncthreads();
        if (tile < ntiles) {
            bf16x8 afrag[2];
#pragma unroll
            for (int kh = 0; kh < 2; ++kh)
                afrag[kh] = *(const bf16x8*)&zs[lm][kh * 32 + q * 8];  // ds_read_b128, <=2-way

            f32x4 acc[4];
#pragma unroll
            for (int nt = 0; nt < 4; ++nt) acc[nt] = (f32x4){0.f, 0.f, 0.f, 0.f};
#pragma unroll
            for (int kh = 0; kh < 2; ++kh)
#pragma unroll
                for (int nt = 0; nt < 4; ++nt)
                    acc[nt] = __builtin_amdgcn_mfma_f32_16x16x32_bf16(
                        afrag[kh], bfrag[nt][kh], acc[nt], 0, 0, 0);

            // epilogue: C row=(q*4+r), col=lm -> UV[node][ncol], bias on U half
#pragma unroll
            for (int nt = 0; nt < 4; ++nt) {
                const int ncol = w * 64 + nt * 16 + lm;
#pragma unroll
                for (int r = 0; r < 4; ++r) {
                    const int node = node0 + q * 4 + r;
                    if (node < n_nodes)
                        UV[(size_t)node * 256 + ncol] = f2bf(acc[nt][r] + bias[nt]);
                }
            }
        }
        __syncthreads();  // WAR on zs
    }
}

// ---------------- Kernel 2: per-edge gather + relu + dot (unchanged logic) ----
__device__ inline float acc2(uint32_t u, uint32_t v, float w0, float w1, float s) {
    float ul = __builtin_bit_cast(float, u << 16);
    float uh = __builtin_bit_cast(float, u & 0xFFFF0000u);
    float vl = __builtin_bit_cast(float, v << 16);
    float vh = __builtin_bit_cast(float, v & 0xFFFF0000u);
    s = fmaf(fmaxf(ul + vl, 0.f), w0, s);
    s = fmaf(fmaxf(uh + vh, 0.f), w1, s);
    return s;
}

__global__ __launch_bounds__(256) void edge_kernel(
    const unsigned short* __restrict__ UV,
    const int* __restrict__ row, const int* __restrict__ col,
    const float* __restrict__ W2, const float* __restrict__ b2,
    float* __restrict__ out, int E)
{
    const int sub = threadIdx.x & 15;           // lane within 16-lane edge-group
    const float4 w2a = *(const float4*)&W2[sub * 8];
    const float4 w2b = *(const float4*)&W2[sub * 8 + 4];
    const float bb = b2[0];

    int g = blockIdx.x * 16 + (threadIdx.x >> 4);
    const int stride = gridDim.x * 16;

    for (; g < E; g += stride) {
        const int r = row[g];
        const int c = col[g];
        uint4 uu = *(const uint4*)(UV + (size_t)r * 256 + sub * 8);          // U half
        uint4 vv = *(const uint4*)(UV + (size_t)c * 256 + 128 + sub * 8);    // V half
        float s = 0.f;
        s = acc2(uu.x, vv.x, w2a.x, w2a.y, s);
        s = acc2(uu.y, vv.y, w2a.z, w2a.w, s);
        s = acc2(uu.z, vv.z, w2b.x, w2b.y, s);
        s = acc2(uu.w, vv.w, w2b.z, w2b.w, s);
        s += __shfl_xor(s, 1, 16);
        s += __shfl_xor(s, 2, 16);
        s += __shfl_xor(s, 4, 16);
        s += __shfl_xor(s, 8, 16);
        if (sub == 0) out[g] = s + bb;
    }
}

extern "C" void kernel_launch(void* const* d_in, const int* in_sizes, int n_in,
                              void* d_out, int out_size, void* d_ws, size_t ws_size,
                              hipStream_t stream) {
    const float* z   = (const float*)d_in[0];
    const int*   row = (const int*)d_in[1];
    const int*   col = (const int*)d_in[2];
    const float* W1  = (const float*)d_in[3];
    const float* b1  = (const float*)d_in[4];
    const float* W2  = (const float*)d_in[5];
    const float* b2  = (const float*)d_in[6];
    float* out = (float*)d_out;

    const int n_nodes = in_sizes[0] / 64;   // z is [N, 64]
    const int E = in_sizes[1];

    unsigned short* UV = (unsigned short*)d_ws;  // [n_nodes][256] bf16 = 51.2 MB

    node_precompute_mfma<<<512, 256, 0, stream>>>(z, W1, b1, UV, n_nodes);

    edge_kernel<<<4096, 256, 0, stream>>>(UV, row, col, W2, b2, out, E);
}